// Round 7
// baseline (43.486 us; speedup 1.0000x reference)
//
#include <hip/hip_runtime.h>
#include <hip/hip_bf16.h>

#define BS_   256
#define NOPS_ 2000
#define NJ_   50
#define NM_   40
#define E_    128
#define H_    128
#define NCOL_ 2001   // 1 + 50*40

typedef _Float16 f16;
using f16x8 = __attribute__((ext_vector_type(8))) _Float16;
using f32x4 = __attribute__((ext_vector_type(4))) float;

// ---------------------------------------------------------------------------
// One kernel, 2 blocks (256 thr, 4 waves) per batch element.
// Phase 1: waves 0-3 jp-tiles, waves 0-2 mp-tiles, wave 3 noop MLP.
// Phase 2: pair-logit tiles with SWAPPED operands: D = W2^T . h1^T, so each
//          lane owns one pair column -> epilogue needs only 2 shfl + 1 store.
// ---------------------------------------------------------------------------
__global__ __launch_bounds__(256, 2) void fjsp_fused(
    const float* __restrict__ ops_emb,
    const float* __restrict__ ma_emb,
    const int*   __restrict__ next_op,
    const int*   __restrict__ amask,
    const float* __restrict__ dummy,
    const float* __restrict__ W1,
    const float* __restrict__ b1,
    const float* __restrict__ W2,
    const float* __restrict__ b2,
    const float* __restrict__ W3,
    const float* __restrict__ b3,
    float* __restrict__ out)
{
  const int bid  = blockIdx.x;
  const int b    = bid >> 1;
  const int sub  = bid & 1;
  const int tid  = threadIdx.x;
  const int lane = tid & 63;
  const int wave = tid >> 6;
  const int g    = lane >> 4;   // 0..3
  const int lr   = lane & 15;   // 0..15

  __shared__ __align__(16) f16 jpL[NJ_][136];   // 272B row stride (4-bank skew)
  __shared__ __align__(16) f16 mpL[NM_][136];
  __shared__ float d1s[128];

  // ---------------- phase 1a: jp tile `wave` (rows 16w..16w+15) ------------
  {
    const int r0 = wave * 16;
    int jr = r0 + lr; if (jr > NJ_ - 1) jr = NJ_ - 1;
    const int idx = next_op[b * NJ_ + jr];
    const float4* ep = reinterpret_cast<const float4*>(
        ops_emb + ((size_t)b * NOPS_ + idx) * E_);
    f16x8 af[4];
    #pragma unroll
    for (int f = 0; f < 4; ++f) {
      const float4 v0 = ep[8 * f + 2 * g];
      const float4 v1 = ep[8 * f + 2 * g + 1];
      f16x8 a;
      a[0] = (f16)v0.x; a[1] = (f16)v0.y; a[2] = (f16)v0.z; a[3] = (f16)v0.w;
      a[4] = (f16)v1.x; a[5] = (f16)v1.y; a[6] = (f16)v1.z; a[7] = (f16)v1.w;
      af[f] = a;
    }
    f32x4 acc[8];
    #pragma unroll
    for (int c = 0; c < 8; ++c) acc[c] = f32x4{0.f, 0.f, 0.f, 0.f};
    #pragma unroll
    for (int f = 0; f < 4; ++f) {
      #pragma unroll
      for (int c = 0; c < 8; ++c) {
        const float* wp = W1 + (size_t)(32 * f + 8 * g) * H_ + 16 * c + lr;
        f16x8 bb;
        #pragma unroll
        for (int i = 0; i < 8; ++i) bb[i] = (f16)wp[(size_t)i * H_];
        acc[c] = __builtin_amdgcn_mfma_f32_16x16x32_f16(af[f], bb, acc[c], 0, 0, 0);
      }
    }
    #pragma unroll
    for (int c = 0; c < 8; ++c) {
      const int col = 16 * c + lr;
      #pragma unroll
      for (int i = 0; i < 4; ++i) {
        const int row = r0 + 4 * g + i;
        if (row < NJ_) jpL[row][col] = (f16)acc[c][i];
      }
    }
  }

  // ---------------- phase 1b: mp tiles (waves 0-2) / noop (wave 3) ---------
  if (wave < 3) {
    const int r0 = wave * 16;
    int mr = r0 + lr; if (mr > NM_ - 1) mr = NM_ - 1;
    const float4* ep = reinterpret_cast<const float4*>(
        ma_emb + ((size_t)b * NM_ + mr) * E_);
    f16x8 af[4];
    #pragma unroll
    for (int f = 0; f < 4; ++f) {
      const float4 v0 = ep[8 * f + 2 * g];
      const float4 v1 = ep[8 * f + 2 * g + 1];
      f16x8 a;
      a[0] = (f16)v0.x; a[1] = (f16)v0.y; a[2] = (f16)v0.z; a[3] = (f16)v0.w;
      a[4] = (f16)v1.x; a[5] = (f16)v1.y; a[6] = (f16)v1.z; a[7] = (f16)v1.w;
      af[f] = a;
    }
    f32x4 acc[8];
    #pragma unroll
    for (int c = 0; c < 8; ++c) {
      const float binit = b1[16 * c + lr];
      acc[c] = f32x4{binit, binit, binit, binit};
    }
    #pragma unroll
    for (int f = 0; f < 4; ++f) {
      #pragma unroll
      for (int c = 0; c < 8; ++c) {
        const float* wp = W1 + (size_t)(E_ + 32 * f + 8 * g) * H_ + 16 * c + lr;
        f16x8 bb;
        #pragma unroll
        for (int i = 0; i < 8; ++i) bb[i] = (f16)wp[(size_t)i * H_];
        acc[c] = __builtin_amdgcn_mfma_f32_16x16x32_f16(af[f], bb, acc[c], 0, 0, 0);
      }
    }
    #pragma unroll
    for (int c = 0; c < 8; ++c) {
      const int col = 16 * c + lr;
      #pragma unroll
      for (int i = 0; i < 4; ++i) {
        const int row = r0 + 4 * g + i;
        if (row < NM_) mpL[row][col] = (f16)acc[c][i];
      }
    }
  } else {
    // ---- noop MLP on wave 3: 2 h-units per lane, 4-way ILP chains ----
    float s0[4] = {0,0,0,0}, s1[4] = {0,0,0,0};
    #pragma unroll 2
    for (int e = 0; e < 2 * E_; e += 4) {
      #pragma unroll
      for (int q = 0; q < 4; ++q) {
        const float dv = dummy[e + q];
        s0[q] = fmaf(dv, W1[(size_t)(e + q) * H_ + lane],      s0[q]);
        s1[q] = fmaf(dv, W1[(size_t)(e + q) * H_ + 64 + lane], s1[q]);
      }
    }
    d1s[lane]      = fmaxf(s0[0]+s0[1]+s0[2]+s0[3] + b1[lane],      0.f);
    d1s[64 + lane] = fmaxf(s1[0]+s1[1]+s1[2]+s1[3] + b1[64 + lane], 0.f);
    asm volatile("s_waitcnt lgkmcnt(0)" ::: "memory");   // in-wave LDS w->r
    __builtin_amdgcn_wave_barrier();
    float t0[4] = {0,0,0,0}, t1[4] = {0,0,0,0};
    #pragma unroll 2
    for (int k = 0; k < H_; k += 4) {
      #pragma unroll
      for (int q = 0; q < 4; ++q) {
        const float dk = d1s[k + q];                     // broadcast read
        t0[q] = fmaf(dk, W2[(size_t)(k + q) * H_ + lane],      t0[q]);
        t1[q] = fmaf(dk, W2[(size_t)(k + q) * H_ + 64 + lane], t1[q]);
      }
    }
    float nv = fmaxf(t0[0]+t0[1]+t0[2]+t0[3] + b2[lane],      0.f) * W3[lane]
             + fmaxf(t1[0]+t1[1]+t1[2]+t1[3] + b2[64 + lane], 0.f) * W3[64 + lane];
    #pragma unroll
    for (int s = 1; s < 64; s <<= 1) nv += __shfl_xor(nv, s);
    if (sub == 0 && lane == 0) out[(size_t)b * NCOL_] = nv + b3[0];
  }

  // ---- W2 fragments (A-operand after swap; same layout as validated) ----
  f16x8 w2f[4][8];
  #pragma unroll
  for (int f = 0; f < 4; ++f) {
    #pragma unroll
    for (int c = 0; c < 8; ++c) {
      const float* wp = W2 + (size_t)(32 * f + 8 * g) * H_ + 16 * c + lr;
      f16x8 bb;
      #pragma unroll
      for (int i = 0; i < 8; ++i) bb[i] = (f16)wp[(size_t)i * H_];
      w2f[f][c] = bb;
    }
  }
  // per-lane h-slice vectors: h = 16c + 4g + {0..3}
  float4 b2v[8], w3v[8];
  #pragma unroll
  for (int c = 0; c < 8; ++c) {
    b2v[c] = *reinterpret_cast<const float4*>(b2 + 16 * c + 4 * g);
    w3v[c] = *reinterpret_cast<const float4*>(W3 + 16 * c + 4 * g);
  }
  const float bias3 = b3[0];

  __syncthreads();

  // ---------------- phase 2: tiles of 16 pairs, lane lr = pair col ---------
  float* __restrict__ outrow = out + (size_t)b * NCOL_ + 1;
  const int tstart = sub ? 63 : 0;
  const int tend   = sub ? 125 : 63;

  #pragma unroll 1
  for (int t = tstart + wave; t < tend; t += 4) {
    const int tp0  = t * 16;
    const int pair = tp0 + lr;
    const int j = pair / 40;
    const int m = pair - j * 40;
    f16x8 afr[4];                                 // B-frag: col = pair
    #pragma unroll
    for (int f = 0; f < 4; ++f) {
      const f16x8 jv = *reinterpret_cast<const f16x8*>(&jpL[j][32 * f + 8 * g]);
      const f16x8 mv = *reinterpret_cast<const f16x8*>(&mpL[m][32 * f + 8 * g]);
      const f16x8 s  = jv + mv;                                // v_pk_add_f16
      afr[f] = __builtin_elementwise_max(s, (f16x8)(f16)0.0f); // v_pk_max_f16
    }
    f32x4 acc[8];
    #pragma unroll
    for (int c = 0; c < 8; ++c)
      acc[c] = f32x4{b2v[c].x, b2v[c].y, b2v[c].z, b2v[c].w};  // b2 in C-init
    #pragma unroll
    for (int f = 0; f < 4; ++f)
      #pragma unroll
      for (int c = 0; c < 8; ++c)    // SWAPPED: A = W2^T frag, B = h1^T frag
        acc[c] = __builtin_amdgcn_mfma_f32_16x16x32_f16(w2f[f][c], afr[f], acc[c], 0, 0, 0);
    // epilogue: each lane owns pair `pair`, h-slice {16c+4g+i}
    float p = 0.f;
    #pragma unroll
    for (int c = 0; c < 8; ++c) {
      p = fmaf(fmaxf(acc[c][0], 0.f), w3v[c].x, p);
      p = fmaf(fmaxf(acc[c][1], 0.f), w3v[c].y, p);
      p = fmaf(fmaxf(acc[c][2], 0.f), w3v[c].z, p);
      p = fmaf(fmaxf(acc[c][3], 0.f), w3v[c].w, p);
    }
    p += __shfl_xor(p, 16);
    p += __shfl_xor(p, 32);
    if (g == 0) outrow[pair] = p + bias3;         // 16-lane coalesced store
  }

  // ---- mask passthrough (int32 bool -> f32), split across the 2 blocks ----
  {
    const int* mrow = amask + (size_t)b * NCOL_;
    float* __restrict__ orow = out + (size_t)BS_ * NCOL_ + (size_t)b * NCOL_;
    const int i0 = sub ? 1001 : 0;
    const int i1 = sub ? NCOL_ : 1001;
    for (int i = i0 + tid; i < i1; i += 256) orow[i] = mrow[i] != 0 ? 1.0f : 0.0f;
  }
}

extern "C" void kernel_launch(void* const* d_in, const int* in_sizes, int n_in,
                              void* d_out, int out_size, void* d_ws, size_t ws_size,
                              hipStream_t stream) {
  (void)in_sizes; (void)n_in; (void)d_ws; (void)ws_size; (void)out_size;
  fjsp_fused<<<dim3(BS_ * 2), dim3(256), 0, stream>>>(
      (const float*)d_in[0],   // ops_emb
      (const float*)d_in[1],   // ma_emb
      (const int*)d_in[2],     // next_op
      (const int*)d_in[3],     // action_mask (bool -> int32)
      (const float*)d_in[4],   // dummy
      (const float*)d_in[5],   // W1
      (const float*)d_in[6],   // b1
      (const float*)d_in[7],   // W2
      (const float*)d_in[8],   // b2
      (const float*)d_in[9],   // W3
      (const float*)d_in[10],  // b3
      (float*)d_out);
}

// Round 8
// 36.719 us; speedup vs baseline: 1.1843x; 1.1843x over previous
//
#include <hip/hip_runtime.h>
#include <hip/hip_bf16.h>

#define BS_   256
#define NOPS_ 2000
#define NJ_   50
#define NM_   40
#define E_    128
#define H_    128
#define NCOL_ 2001   // 1 + 50*40

typedef _Float16 f16;
using f16x8 = __attribute__((ext_vector_type(8))) _Float16;
using f16x4 = __attribute__((ext_vector_type(4))) _Float16;
using f32x4 = __attribute__((ext_vector_type(4))) float;

// ---------------------------------------------------------------------------
// Single kernel, one block (512 thr, 8 waves) per batch element.
// dummy is folded in as jp-row 50 / mp-row 40; noop logit = pair index 2000.
// Phase 1: waves 0-1: W1lo frags->regs + jp tiles {0,1}/{2,3}
//          waves 2-3: W1hi frags->regs + mp tiles {0,1}/{2}
//          waves 4-5: W2 frags (16 each) -> LDS frag buffer (conflict-free)
//          wave  7  : action-mask passthrough (overlapped)
// Phase 2: all 8 waves: W2 frags LDS->regs, 126 tiles of 16 pairs,
//          swapped MFMA (D = W2^T.h1^T), 2-shfl epilogue, coalesced store.
// ---------------------------------------------------------------------------
__global__ __launch_bounds__(512, 2) void fjsp_fused(
    const float* __restrict__ ops_emb,
    const float* __restrict__ ma_emb,
    const int*   __restrict__ next_op,
    const int*   __restrict__ amask,
    const float* __restrict__ dummy,
    const float* __restrict__ W1,
    const float* __restrict__ b1,
    const float* __restrict__ W2,
    const float* __restrict__ b2,
    const float* __restrict__ W3,
    const float* __restrict__ b3,
    float* __restrict__ out)
{
  const int b    = blockIdx.x;
  const int tid  = threadIdx.x;
  const int lane = tid & 63;
  const int wave = tid >> 6;
  const int g    = lane >> 4;   // 0..3
  const int lr   = lane & 15;   // 0..15

  // W2 fragment buffer: [t=8f+c][lane][8 f16] -> lane*16B: conflict-free b128
  __shared__ __align__(16) f16 fragL[32 * 64 * 8];       // 32 KB
  // 140 f16 = 280 B row stride: bank step 6 per row -> <=2-way on b64 reads
  __shared__ __align__(16) f16 jpL[51][140];             // 14.0 KB
  __shared__ __align__(16) f16 mpL[41][140];             // 11.2 KB

  // ========================= phase 1 =========================
  if (wave < 4) {
    const bool  isJ   = (wave < 2);
    const size_t ebase = isJ ? 0 : (size_t)E_ * H_;
    // my W1-half fragments -> regs (one strided load set per wave)
    f16x8 wfr[4][8];
    #pragma unroll
    for (int f = 0; f < 4; ++f) {
      #pragma unroll
      for (int c = 0; c < 8; ++c) {
        const float* wp = W1 + ebase + (size_t)(32 * f + 8 * g) * H_ + 16 * c + lr;
        f16x8 bb;
        #pragma unroll
        for (int i = 0; i < 8; ++i) bb[i] = (f16)wp[(size_t)i * H_];
        wfr[f][c] = bb;
      }
    }
    float b1r[8];
    #pragma unroll
    for (int c = 0; c < 8; ++c) b1r[c] = isJ ? 0.f : b1[16 * c + lr];

    const int t0 = (wave == 0) ? 0 : (wave == 1) ? 2 : (wave == 2) ? 0 : 2;
    const int nt = (wave == 3) ? 1 : 2;
    for (int q = 0; q < nt; ++q) {
      const int r0 = (t0 + q) * 16;
      const float* src;
      if (isJ) {
        int jr = r0 + lr; if (jr > 50) jr = 50;
        src = (jr == 50) ? dummy
                         : ops_emb + ((size_t)b * NOPS_ + next_op[b * NJ_ + jr]) * E_;
      } else {
        int mr = r0 + lr; if (mr > 40) mr = 40;
        src = (mr == 40) ? (dummy + E_)
                         : ma_emb + ((size_t)b * NM_ + mr) * E_;
      }
      const float4* ep = reinterpret_cast<const float4*>(src);
      f16x8 af[4];
      #pragma unroll
      for (int f = 0; f < 4; ++f) {
        const float4 v0 = ep[8 * f + 2 * g];
        const float4 v1 = ep[8 * f + 2 * g + 1];
        f16x8 a;
        a[0] = (f16)v0.x; a[1] = (f16)v0.y; a[2] = (f16)v0.z; a[3] = (f16)v0.w;
        a[4] = (f16)v1.x; a[5] = (f16)v1.y; a[6] = (f16)v1.z; a[7] = (f16)v1.w;
        af[f] = a;
      }
      f32x4 acc[8];
      #pragma unroll
      for (int c = 0; c < 8; ++c) acc[c] = f32x4{b1r[c], b1r[c], b1r[c], b1r[c]};
      #pragma unroll
      for (int f = 0; f < 4; ++f)
        #pragma unroll
        for (int c = 0; c < 8; ++c)
          acc[c] = __builtin_amdgcn_mfma_f32_16x16x32_f16(af[f], wfr[f][c], acc[c], 0, 0, 0);
      #pragma unroll
      for (int c = 0; c < 8; ++c) {
        const int col = 16 * c + lr;
        #pragma unroll
        for (int i = 0; i < 4; ++i) {
          const int row = r0 + 4 * g + i;
          if (isJ) { if (row < 51) jpL[row][col] = (f16)acc[c][i]; }
          else     { if (row < 41) mpL[row][col] = (f16)acc[c][i]; }
        }
      }
    }
  } else if (wave < 6) {
    // W2 fragment loader: 16 frags per wave -> LDS, conflict-free b128 writes
    #pragma unroll 4
    for (int q = 0; q < 16; ++q) {
      const int t = (wave - 4) * 16 + q;
      const int f = t >> 3, c = t & 7;
      const float* wp = W2 + (size_t)(32 * f + 8 * g) * H_ + 16 * c + lr;
      f16x8 bb;
      #pragma unroll
      for (int i = 0; i < 8; ++i) bb[i] = (f16)wp[(size_t)i * H_];
      *reinterpret_cast<f16x8*>(&fragL[((size_t)t * 64 + lane) * 8]) = bb;
    }
  } else if (wave == 7) {
    // action-mask passthrough (int32 bool -> f32), overlapped with phase 1
    const int* mrow = amask + (size_t)b * NCOL_;
    float* __restrict__ orow = out + (size_t)BS_ * NCOL_ + (size_t)b * NCOL_;
    #pragma unroll 4
    for (int i = lane; i < NCOL_; i += 64) orow[i] = mrow[i] != 0 ? 1.0f : 0.0f;
  }
  __syncthreads();

  // ========================= phase 2 =========================
  // W2 fragments from LDS (32 x b128, conflict-free)
  f16x8 w2f[4][8];
  #pragma unroll
  for (int f = 0; f < 4; ++f)
    #pragma unroll
    for (int c = 0; c < 8; ++c)
      w2f[f][c] = *reinterpret_cast<const f16x8*>(
          &fragL[((size_t)(f * 8 + c) * 64 + lane) * 8]);
  float4 b2v[8], w3v[8];
  #pragma unroll
  for (int c = 0; c < 8; ++c) {
    b2v[c] = *reinterpret_cast<const float4*>(b2 + 16 * c + 4 * g);
    w3v[c] = *reinterpret_cast<const float4*>(W3 + 16 * c + 4 * g);
  }
  const float bias3 = b3[0];
  float* __restrict__ outb = out + (size_t)b * NCOL_;

  #pragma unroll 1
  for (int t = wave; t < 126; t += 8) {
    const int p  = t * 16 + lr;               // pair index, 2000 = noop
    const int p2 = (p < 2000) ? p : 2000;
    int j, m;
    if (p2 == 2000) { j = 50; m = 40; }
    else            { j = p2 / 40; m = p2 - j * 40; }
    f16x8 afr[4];
    #pragma unroll
    for (int f = 0; f < 4; ++f) {
      const f16x4 jlo = *reinterpret_cast<const f16x4*>(&jpL[j][32 * f + 8 * g]);
      const f16x4 jhi = *reinterpret_cast<const f16x4*>(&jpL[j][32 * f + 8 * g + 4]);
      const f16x4 mlo = *reinterpret_cast<const f16x4*>(&mpL[m][32 * f + 8 * g]);
      const f16x4 mhi = *reinterpret_cast<const f16x4*>(&mpL[m][32 * f + 8 * g + 4]);
      const f16x4 z   = {(f16)0.f, (f16)0.f, (f16)0.f, (f16)0.f};
      const f16x4 slo = __builtin_elementwise_max(jlo + mlo, z);
      const f16x4 shi = __builtin_elementwise_max(jhi + mhi, z);
      afr[f] = __builtin_shufflevector(slo, shi, 0, 1, 2, 3, 4, 5, 6, 7);
    }
    f32x4 acc[8];
    #pragma unroll
    for (int c = 0; c < 8; ++c)
      acc[c] = f32x4{b2v[c].x, b2v[c].y, b2v[c].z, b2v[c].w};   // b2 in C-init
    #pragma unroll
    for (int f = 0; f < 4; ++f)
      #pragma unroll
      for (int c = 0; c < 8; ++c)     // SWAPPED: A = W2^T frag, B = h1^T frag
        acc[c] = __builtin_amdgcn_mfma_f32_16x16x32_f16(w2f[f][c], afr[f], acc[c], 0, 0, 0);
    // epilogue: lane owns pair p, h-slice {16c+4g+i}
    float pv = 0.f;
    #pragma unroll
    for (int c = 0; c < 8; ++c) {
      pv = fmaf(fmaxf(acc[c][0], 0.f), w3v[c].x, pv);
      pv = fmaf(fmaxf(acc[c][1], 0.f), w3v[c].y, pv);
      pv = fmaf(fmaxf(acc[c][2], 0.f), w3v[c].z, pv);
      pv = fmaf(fmaxf(acc[c][3], 0.f), w3v[c].w, pv);
    }
    pv += __shfl_xor(pv, 16);
    pv += __shfl_xor(pv, 32);
    if (g == 0 && p <= 2000)
      outb[(p == 2000) ? 0 : (p + 1)] = pv + bias3;   // coalesced 16-lane store
  }
}

extern "C" void kernel_launch(void* const* d_in, const int* in_sizes, int n_in,
                              void* d_out, int out_size, void* d_ws, size_t ws_size,
                              hipStream_t stream) {
  (void)in_sizes; (void)n_in; (void)d_ws; (void)ws_size; (void)out_size;
  fjsp_fused<<<dim3(BS_), dim3(512), 0, stream>>>(
      (const float*)d_in[0],   // ops_emb
      (const float*)d_in[1],   // ma_emb
      (const int*)d_in[2],     // next_op
      (const int*)d_in[3],     // action_mask (bool -> int32)
      (const float*)d_in[4],   // dummy
      (const float*)d_in[5],   // W1
      (const float*)d_in[6],   // b1
      (const float*)d_in[7],   // W2
      (const float*)d_in[8],   // b2
      (const float*)d_in[9],   // W3
      (const float*)d_in[10],  // b3
      (float*)d_out);
}